// Round 5
// baseline (143.892 us; speedup 1.0000x reference)
//
#include <hip/hip_runtime.h>

// WaveletLoss: 3-level Haar DWT + soft-threshold + weighted mean-abs-diff.
// B=64, C=1, H=W=512.
// R4: copy-ubench-shaped load stream. Wave owns 8-row x 256-col strips; every
// load instr is one contiguous 1024B segment (lane li -> col 4*li of one row).
// Levels 1-2 close fully in-lane (lane holds pixel cols 4li..4li+3); level 3
// via one __shfl_xor(1). Explicit double-buffered software pipeline (prefetch
// row-pair rp+2 while computing rp). 1024 blocks, 2 strips/wave, <=128 VGPR.

#define IMG_W 512
#define N_BATCH 64

#define THR1 (50.0f / 255.0f)
#define THR2 (25.0f / 255.0f)
#define THR3 (12.5f / 255.0f)

#define NBLK 1024
#define N_WAVES (NBLK * 4)      // 4096
#define N_TILES 8192            // 64 img * 64 strips * 2 col-halves

__device__ __forceinline__ float softthr(float x, float thr) {
    float m = fmaxf(fabsf(x) - thr, 0.0f);
    return copysignf(m, x);
}

__device__ __forceinline__ float detail_term(float p, float t, float thr) {
    return fabsf(softthr(p, thr) - softthr(t, thr));
}

__device__ __forceinline__ void haar_quad(float a, float b, float c, float d,
                                          float& cA, float& cH, float& cV, float& cD) {
    cA = 0.5f * (a + b + c + d);
    cH = 0.5f * (a + b - c - d);
    cV = 0.5f * (a - b + c - d);
    cD = 0.5f * (a - b - c + d);
}

__device__ __forceinline__ float4 ld4(const float* p) { return *(const float4*)p; }

__global__ __launch_bounds__(256, 4)
void wavelet_main(const float* __restrict__ pred,
                  const float* __restrict__ target,
                  float* __restrict__ ws) {
    constexpr float W1 = 1.0f / (1.0f * 3.0f * (float)(N_BATCH * 256 * 256));
    constexpr float W2 = 1.0f / (2.0f * 3.0f * (float)(N_BATCH * 128 * 128));
    constexpr float W3 = 1.0f / (3.0f * 3.0f * (float)(N_BATCH * 64 * 64));

    const int wid = blockIdx.x * 4 + (threadIdx.x >> 6);
    const int li  = threadIdx.x & 63;

    float acc = 0.0f;

    #pragma unroll
    for (int t = 0; t < 2; ++t) {
        const int T     = wid + t * N_WAVES;      // tile id 0..8191
        const int img   = T >> 7;
        const int rem   = T & 127;
        const int half  = rem & 1;
        const int strip = rem >> 1;               // 8-row strip 0..63

        const size_t off = (size_t)img * (512 * 512)
                         + (size_t)strip * 8 * IMG_W
                         + half * 256 + 4 * li;
        const float* pb = pred + off;
        const float* tb = target + off;

        // double-buffered row-pair pipeline: rp covers pixel rows 2rp,2rp+1
        float4 Pa[2], Pb[2], Ta[2], Tb[2];
        Pa[0] = ld4(pb);            Pb[0] = ld4(pb + IMG_W);
        Ta[0] = ld4(tb);            Tb[0] = ld4(tb + IMG_W);
        Pa[1] = ld4(pb + 1024);     Pb[1] = ld4(pb + 1536);
        Ta[1] = ld4(tb + 1024);     Tb[1] = ld4(tb + 1536);

        float s1 = 0.0f, s2 = 0.0f;
        float cA1p[4][2], cA1t[4][2];

        #pragma unroll
        for (int rp = 0; rp < 4; ++rp) {
            const int bsel = rp & 1;
            const float4 p0 = Pa[bsel], p1 = Pb[bsel];
            const float4 q0 = Ta[bsel], q1 = Tb[bsel];

            if (rp < 2) {  // prefetch row-pair rp+2 into the buffer just freed
                const int o = (rp + 2) * 1024;
                Pa[bsel] = ld4(pb + o);         Pb[bsel] = ld4(pb + o + IMG_W);
                Ta[bsel] = ld4(tb + o);         Tb[bsel] = ld4(tb + o + IMG_W);
            }

            float cA, cH, cV, cD, cAt, cHt, cVt, cDt;
            // quad: pixel cols (4li, 4li+1)
            haar_quad(p0.x, p0.y, p1.x, p1.y, cA, cH, cV, cD);
            haar_quad(q0.x, q0.y, q1.x, q1.y, cAt, cHt, cVt, cDt);
            s1 += detail_term(cH, cHt, THR1) + detail_term(cV, cVt, THR1) + detail_term(cD, cDt, THR1);
            cA1p[rp][0] = cA; cA1t[rp][0] = cAt;
            // quad: pixel cols (4li+2, 4li+3)
            haar_quad(p0.z, p0.w, p1.z, p1.w, cA, cH, cV, cD);
            haar_quad(q0.z, q0.w, q1.z, q1.w, cAt, cHt, cVt, cDt);
            s1 += detail_term(cH, cHt, THR1) + detail_term(cV, cVt, THR1) + detail_term(cD, cDt, THR1);
            cA1p[rp][1] = cA; cA1t[rp][1] = cAt;
        }

        // ---- level 2: two quads fully in-lane ----
        float cA2p[2], cA2t[2];
        {
            float cH, cV, cD, cHt, cVt, cDt;
            haar_quad(cA1p[0][0], cA1p[0][1], cA1p[1][0], cA1p[1][1], cA2p[0], cH, cV, cD);
            haar_quad(cA1t[0][0], cA1t[0][1], cA1t[1][0], cA1t[1][1], cA2t[0], cHt, cVt, cDt);
            s2 += detail_term(cH, cHt, THR2) + detail_term(cV, cVt, THR2) + detail_term(cD, cDt, THR2);
            haar_quad(cA1p[2][0], cA1p[2][1], cA1p[3][0], cA1p[3][1], cA2p[1], cH, cV, cD);
            haar_quad(cA1t[2][0], cA1t[2][1], cA1t[3][0], cA1t[3][1], cA2t[1], cHt, cVt, cDt);
            s2 += detail_term(cH, cHt, THR2) + detail_term(cV, cVt, THR2) + detail_term(cD, cDt, THR2);
        }

        // ---- level 3: horizontal neighbor via shfl_xor(1), vertical in-lane ----
        float s3;
        {
            const float bP = __shfl_xor(cA2p[0], 1);
            const float dP = __shfl_xor(cA2p[1], 1);
            const float bT = __shfl_xor(cA2t[0], 1);
            const float dT = __shfl_xor(cA2t[1], 1);
            float cA, cH, cV, cD, cAt, cHt, cVt, cDt;
            haar_quad(cA2p[0], bP, cA2p[1], dP, cA, cH, cV, cD);
            haar_quad(cA2t[0], bT, cA2t[1], dT, cAt, cHt, cVt, cDt);
            s3 = detail_term(cH, cHt, THR3) + detail_term(cV, cVt, THR3) + detail_term(cD, cDt, THR3);
        }
        const float w3 = (li & 1) ? 0.0f : W3;

        acc += W1 * s1 + W2 * s2 + w3 * s3;
    }

    // wave reduction (64 lanes)
    #pragma unroll
    for (int off = 32; off > 0; off >>= 1)
        acc += __shfl_down(acc, off, 64);

    __shared__ float wave_sums[4];
    const int lane_b = threadIdx.x & 63;
    const int wave_b = threadIdx.x >> 6;
    if (lane_b == 0) wave_sums[wave_b] = acc;
    __syncthreads();
    if (threadIdx.x == 0)
        ws[blockIdx.x] = wave_sums[0] + wave_sums[1] + wave_sums[2] + wave_sums[3];
}

__global__ __launch_bounds__(256)
void wavelet_reduce(const float* __restrict__ ws, float* __restrict__ out) {
    const int tidx = threadIdx.x;
    float v = 0.0f;
    #pragma unroll
    for (int k = 0; k < NBLK / 256; ++k)
        v += ws[tidx + k * 256];

    #pragma unroll
    for (int off = 32; off > 0; off >>= 1)
        v += __shfl_down(v, off, 64);

    __shared__ float wave_sums[4];
    const int lane = tidx & 63;
    const int wave = tidx >> 6;
    if (lane == 0) wave_sums[wave] = v;
    __syncthreads();
    if (tidx == 0)
        out[0] = wave_sums[0] + wave_sums[1] + wave_sums[2] + wave_sums[3];
}

extern "C" void kernel_launch(void* const* d_in, const int* in_sizes, int n_in,
                              void* d_out, int out_size, void* d_ws, size_t ws_size,
                              hipStream_t stream) {
    const float* pred   = (const float*)d_in[0];
    const float* target = (const float*)d_in[1];
    float* out = (float*)d_out;
    float* ws  = (float*)d_ws;   // NBLK floats = 4 KB

    wavelet_main<<<NBLK, 256, 0, stream>>>(pred, target, ws);
    wavelet_reduce<<<1, 256, 0, stream>>>(ws, out);
}